// Round 16
// baseline (60.117 us; speedup 1.0000x reference)
//
#include <hip/hip_runtime.h>
#include <hip/hip_fp16.h>

// NCC loss, window 9, zero-padded separable box sums.
// Shapes: (2,1,160,160,160) f32. Output: scalar f32.
//
// K1: SINGLE-WAVE blocks (64 threads): barriers are free within one wave,
//     ~16 independent blocks/CU hide latency by block-parallelism (all
//     5-wave variants pinned at ~40 us with barrier-coupled waves).
//     Tile 8h x 32w x 1d: exactly 1 W-task + 1 H-task per thread.
//     wsl rows padded to 40 halves (80 B) -> all LDS access <=2-way.
//     A in FP8 e4m3 (2D sums <= 81 < 448). XCD swizzle: 32000 = 8*4000,
//     each XCD owns 40 contiguous (batch,d) slices.
// K2: D-axis sliding-window sum, 4 voxels/thread via 4B uint fp8 loads,
//     SEG=10 -> 800 blocks (proven 12.4 us).
// ws layout: A8[2][5][VOL] bytes (41 MB) | partials[800] f32

#define DIM 160
#define HW  (160 * 160)
#define VOL (160 * 160 * 160)
#define NBATCH 2
#define TH 8                   // output rows per K1 block
#define TW 32                  // output cols per K1 block
#define SRP 40                 // padded row stride (halves)
#define SEG 10
#define NSEG (DIM / SEG)       // 16
#define NK2BLK 800

struct __align__(16) h8 { __half2 a, b, c, d; };
struct __align__(8) h4 { __half2 a, b; };
typedef float v2f __attribute__((ext_vector_type(2)));

__device__ inline float4 dec8(unsigned int u) {
    v2f lo = __builtin_amdgcn_cvt_pk_f32_fp8((int)u, false);
    v2f hi = __builtin_amdgcn_cvt_pk_f32_fp8((int)u, true);
    return make_float4(lo[0], lo[1], hi[0], hi[1]);
}

__device__ inline unsigned int enc8(float a, float b, float c, float d) {
    int u = __builtin_amdgcn_cvt_pk_fp8_f32(a, b, 0, false);
    u = __builtin_amdgcn_cvt_pk_fp8_f32(c, d, u, true);
    return (unsigned int)u;
}

__global__ __launch_bounds__(64) void k1_boxsum2d(const float* __restrict__ I,
                                                  const float* __restrict__ J,
                                                  unsigned char* __restrict__ A8) {
    __shared__ __half wsl[5][16][SRP];   // 6400 B

    const int tid = threadIdx.x;
    // bijective XCD swizzle over 32000 blocks (8 * 4000); each XCD owns
    // 40 contiguous (batch,d) slices -> slice data L2-resident per XCD.
    const int orig = blockIdx.x;
    const int wgid = (orig & 7) * 4000 + (orig >> 3);
    const int tx = wgid % 5;
    int rest = wgid / 5;
    const int ty = rest % 20;
    rest /= 20;
    const int d = rest % DIM;
    const int batch = rest / DIM;
    const int h0 = ty * TH, w0 = tx * TW;
    const float* Ib = I + (size_t)batch * VOL + (size_t)d * HW;
    const float* Jb = J + (size_t)batch * VOL + (size_t)d * HW;

    // ---- W-stage: exactly 64 tasks = 16 rows x 4 groups of 8 outputs ----
    {
        const int r = tid >> 2, g = tid & 3;
        const int gh = h0 - 4 + r;
        const int gw = w0 + 8 * g - 4;   // 4-aligned
        __half* wrow = &wsl[0][r][8 * g];

        if (gh < 0 || gh >= DIM) {
            const __half2 hz = __float2half2_rn(0.f);
            h8 z; z.a = hz; z.b = hz; z.c = hz; z.d = hz;
#pragma unroll
            for (int ch = 0; ch < 5; ++ch)
                *(h8*)(wrow + ch * (16 * SRP)) = z;
        } else {
            const float* pI = Ib + gh * DIM;
            const float* pJ = Jb + gh * DIM;
            float a[16], b[16];
#pragma unroll
            for (int q = 0; q < 4; ++q) {
                int c0 = gw + 4 * q;     // quad fully in [0,160) or fully out
                if (c0 >= 0 && c0 < DIM) {
                    *(float4*)&a[4 * q] = *(const float4*)(pI + c0);
                    *(float4*)&b[4 * q] = *(const float4*)(pJ + c0);
                } else {
                    *(float4*)&a[4 * q] = make_float4(0.f, 0.f, 0.f, 0.f);
                    *(float4*)&b[4 * q] = make_float4(0.f, 0.f, 0.f, 0.f);
                }
            }
#define PROC(CH, VAL)                                                       \
            {                                                               \
                float o[8];                                                 \
                float ss = 0.f;                                             \
                _Pragma("unroll")                                           \
                for (int k = 0; k < 9; ++k) { ss += (VAL); }                \
                o[0] = ss;                                                  \
                _Pragma("unroll")                                           \
                for (int j = 1; j < 8; ++j) {                               \
                    int k = j + 8; float add_ = (VAL);                      \
                    k = j - 1;     float sub_ = (VAL);                      \
                    ss += add_ - sub_;                                      \
                    o[j] = ss;                                              \
                }                                                           \
                h8 v;                                                       \
                v.a = __floats2half2_rn(o[0], o[1]);                        \
                v.b = __floats2half2_rn(o[2], o[3]);                        \
                v.c = __floats2half2_rn(o[4], o[5]);                        \
                v.d = __floats2half2_rn(o[6], o[7]);                        \
                *(h8*)(wrow + CH * (16 * SRP)) = v;                         \
            }
            PROC(0, a[k])
            PROC(1, b[k])
            PROC(2, a[k] * a[k])
            PROC(3, b[k] * b[k])
            PROC(4, a[k] * b[k])
#undef PROC
        }
    }
    __syncthreads();   // single wave: compiles to waitcnt only

    // ---- H-stage: exactly 64 tasks = 8 rows x 8 w-quads, fp8 uint store ----
    {
        const int q = tid & 7, r8 = tid >> 3;
        const size_t ob = (size_t)batch * 5 * VOL + (size_t)d * HW +
                          (size_t)(h0 + r8) * DIM + w0 + 4 * q;
#pragma unroll
        for (int ch = 0; ch < 5; ++ch) {
            const __half2* col = (const __half2*)&wsl[ch][r8][0] + 2 * q;
            h4 v = *(const h4*)col;
            __half2 sa = v.a, sb = v.b;
#pragma unroll
            for (int k = 1; k < 9; ++k) {
                h4 u = *(const h4*)(col + k * (SRP / 2));
                sa = __hadd2(sa, u.a);
                sb = __hadd2(sb, u.b);
            }
            float2 f0 = __half22float2(sa);
            float2 f1 = __half22float2(sb);
            *(unsigned int*)(A8 + ob + (size_t)ch * VOL) =
                enc8(f0.x, f0.y, f1.x, f1.y);
        }
    }
}

__device__ inline void cc_accum(float s0, float s1, float s2, float s3,
                                float s4, float& acc) {
    const float inv_wsz = 1.0f / 729.0f;
    float cross = s4 - s0 * s1 * inv_wsz;
    float Ivar  = s2 - s0 * s0 * inv_wsz;
    float Jvar  = s3 - s1 * s1 * inv_wsz;
    float cc = cross * cross * __builtin_amdgcn_rcpf(Ivar * Jvar + 1e-5f);
    acc += fminf(fmaxf(cc, 0.0f), 1.0f);
}

__global__ __launch_bounds__(256) void k2_dsum_final(const unsigned char* __restrict__ A8,
                                                     float* __restrict__ partial) {
    const int batch = blockIdx.y;
    const unsigned int* B = (const unsigned int*)(A8 + (size_t)batch * 5 * VOL);
    const int PLW = VOL / 4;                 // uint plane stride
    const int HWW = HW / 4;                  // uint slice stride
    int t = blockIdx.x * 256 + threadIdx.x;  // < 40*160*16 = 102400
    int wq = t % 40;
    int rest = t / 40;
    int h = rest % DIM;
    int seg = rest / DIM;                    // 0..15
    int d0 = seg * SEG;
    const int base = h * 40 + wq;

    float4 s0 = {0,0,0,0}, s1 = {0,0,0,0}, s2 = {0,0,0,0},
           s3 = {0,0,0,0}, s4 = {0,0,0,0};
#define ACC4(sv, ch, idx, sgn)                                              \
    {                                                                       \
        float4 v_ = dec8(B[(ch) * PLW + (idx)]);                            \
        sv.x sgn v_.x; sv.y sgn v_.y; sv.z sgn v_.z; sv.w sgn v_.w;         \
    }
#pragma unroll
    for (int k = -4; k <= 4; ++k) {
        int dd = d0 + k;
        if (dd >= 0) {
            int idx = base + dd * HWW;
            ACC4(s0, 0, idx, +=) ACC4(s1, 1, idx, +=) ACC4(s2, 2, idx, +=)
            ACC4(s3, 3, idx, +=) ACC4(s4, 4, idx, +=)
        }
    }

    float acc = 0.f;
    for (int d = d0; d < d0 + SEG; ++d) {
        cc_accum(s0.x, s1.x, s2.x, s3.x, s4.x, acc);
        cc_accum(s0.y, s1.y, s2.y, s3.y, s4.y, acc);
        cc_accum(s0.z, s1.z, s2.z, s3.z, s4.z, acc);
        cc_accum(s0.w, s1.w, s2.w, s3.w, s4.w, acc);
        int lead = d + 5, trail = d - 4;
        if (lead < DIM) {
            int li = base + lead * HWW;
            ACC4(s0, 0, li, +=) ACC4(s1, 1, li, +=) ACC4(s2, 2, li, +=)
            ACC4(s3, 3, li, +=) ACC4(s4, 4, li, +=)
        }
        if (trail >= 0) {
            int ti = base + trail * HWW;
            ACC4(s0, 0, ti, -=) ACC4(s1, 1, ti, -=) ACC4(s2, 2, ti, -=)
            ACC4(s3, 3, ti, -=) ACC4(s4, 4, ti, -=)
        }
    }
#undef ACC4

#pragma unroll
    for (int off = 32; off > 0; off >>= 1) acc += __shfl_down(acc, off);
    __shared__ float ws4[4];
    if ((threadIdx.x & 63) == 0) ws4[threadIdx.x >> 6] = acc;
    __syncthreads();
    if (threadIdx.x == 0)
        partial[batch * 400 + blockIdx.x] = ws4[0] + ws4[1] + ws4[2] + ws4[3];
}

__global__ __launch_bounds__(256) void final_reduce(const float* __restrict__ partial,
                                                    int n, float* __restrict__ out) {
    float a = 0.f;
    for (int i = threadIdx.x; i < n; i += 256) a += partial[i];
#pragma unroll
    for (int off = 32; off > 0; off >>= 1) a += __shfl_down(a, off);
    __shared__ float ws4[4];
    if ((threadIdx.x & 63) == 0) ws4[threadIdx.x >> 6] = a;
    __syncthreads();
    if (threadIdx.x == 0)
        out[0] = 1.0f - (ws4[0] + ws4[1] + ws4[2] + ws4[3]) *
                            (1.0f / (float)(NBATCH * VOL));
}

extern "C" void kernel_launch(void* const* d_in, const int* in_sizes, int n_in,
                              void* d_out, int out_size, void* d_ws, size_t ws_size,
                              hipStream_t stream) {
    const float* I = (const float*)d_in[0];
    const float* J = (const float*)d_in[1];
    float* out = (float*)d_out;

    unsigned char* A8 = (unsigned char*)d_ws;                  // [2][5][VOL] fp8
    float* partial = (float*)(A8 + (size_t)NBATCH * 5 * VOL);  // [800]

    k1_boxsum2d<<<20 * 5 * DIM * NBATCH, 64, 0, stream>>>(I, J, A8);
    dim3 g2(400, NBATCH);                  // 800 blocks
    k2_dsum_final<<<g2, 256, 0, stream>>>(A8, partial);
    final_reduce<<<1, 256, 0, stream>>>(partial, NK2BLK, out);
}

// Round 17
// 53.891 us; speedup vs baseline: 1.1155x; 1.1155x over previous
//
#include <hip/hip_runtime.h>
#include <hip/hip_fp16.h>

// NCC loss, window 9, zero-padded separable box sums.
// Shapes: (2,1,160,160,160) f32. Output: scalar f32.
//
// MEASURED-BEST configuration (rounds 9 & 15, both 53.9 us):
// K1 ~39.5 us, K2 ~12.4 us, final ~1.5 us.
//
// K1: per d-slice fused W+H 2D 9x9 box sum of 5 product channels.
//     TH=8: W-stage exactly 320 tasks, H-stage 4-voxel fp8 stores.
//     wsum fp16 LDS 25.6 KB (6 blocks/CU), 0 bank conflicts; A in FP8
//     e4m3 (2D sums <= 81 < 448; absmax 0.0 vs 1.9e-2 threshold).
//     Bijective XCD swizzle 8x800.
//     [floor note: 8 structural variants (occupancy 16-67%, traffic
//      74-146 MB, 1-5 wave blocks, pipelined/packed/dbuf) all land
//      39-43 us; no pipe >50% busy. Issue/latency-mix floor.]
// K2: D-axis sliding-window sum, 4 voxels/thread via 4B uint fp8 loads,
//     SEG=10 -> 800 blocks.
// ws layout: A8[2][5][VOL] bytes (41 MB) | partials[800] f32

#define DIM 160
#define HW  (160 * 160)
#define VOL (160 * 160 * 160)
#define NBATCH 2
#define TH 8                   // output rows per K1 block
#define SR 16                  // staged rows = TH + 8
#define THB 320
#define SEG 10
#define NSEG (DIM / SEG)       // 16
#define NK2BLK 800

struct __align__(16) h8 { __half2 a, b, c, d; };
struct __align__(8) h4 { __half2 a, b; };
typedef float v2f __attribute__((ext_vector_type(2)));

__device__ inline float4 dec8(unsigned int u) {
    v2f lo = __builtin_amdgcn_cvt_pk_f32_fp8((int)u, false);
    v2f hi = __builtin_amdgcn_cvt_pk_f32_fp8((int)u, true);
    return make_float4(lo[0], lo[1], hi[0], hi[1]);
}

__device__ inline unsigned int enc8(float a, float b, float c, float d) {
    int u = __builtin_amdgcn_cvt_pk_fp8_f32(a, b, 0, false);
    u = __builtin_amdgcn_cvt_pk_fp8_f32(c, d, u, true);
    return (unsigned int)u;
}

__global__ __launch_bounds__(THB) void k1_boxsum2d(const float* __restrict__ I,
                                                   const float* __restrict__ J,
                                                   unsigned char* __restrict__ A8) {
    __shared__ __half wsl[5][SR][DIM];   // 25600 B

    const int tid = threadIdx.x;
    // bijective XCD swizzle over 6400 blocks (8 * 800)
    const int orig = blockIdx.x;
    const int wgid = (orig & 7) * 800 + (orig >> 3);
    const int ty = wgid % 20;
    const int rest = wgid / 20;
    const int d = rest % DIM;
    const int batch = rest / DIM;
    const int h0 = ty * TH;
    const float* Ib = I + (size_t)batch * VOL + (size_t)d * HW;
    const float* Jb = J + (size_t)batch * VOL + (size_t)d * HW;

    // ---- W-stage: exactly 320 tasks = 16 rows x 20 groups of 8 outputs ----
    {
        const int r = tid / 20, g = tid % 20;
        const int gh = h0 - 4 + r;
        const int gw = 8 * g - 4;        // 4-aligned
        __half* wrow = &wsl[0][0][0] + (r * DIM + 8 * g);

        if (gh < 0 || gh >= DIM) {
            const __half2 hz = __float2half2_rn(0.f);
            h8 z; z.a = hz; z.b = hz; z.c = hz; z.d = hz;
#pragma unroll
            for (int ch = 0; ch < 5; ++ch)
                *(h8*)(wrow + ch * (SR * DIM)) = z;
        } else {
            const float* pI = Ib + gh * DIM;
            const float* pJ = Jb + gh * DIM;
            float a[16], b[16];
#pragma unroll
            for (int q = 0; q < 4; ++q) {
                int c0 = gw + 4 * q;     // quad fully in [0,160) or fully out
                if (c0 >= 0 && c0 < DIM) {
                    *(float4*)&a[4 * q] = *(const float4*)(pI + c0);
                    *(float4*)&b[4 * q] = *(const float4*)(pJ + c0);
                } else {
                    *(float4*)&a[4 * q] = make_float4(0.f, 0.f, 0.f, 0.f);
                    *(float4*)&b[4 * q] = make_float4(0.f, 0.f, 0.f, 0.f);
                }
            }
#define PROC(CH, VAL)                                                       \
            {                                                               \
                float o[8];                                                 \
                float ss = 0.f;                                             \
                _Pragma("unroll")                                           \
                for (int k = 0; k < 9; ++k) { ss += (VAL); }                \
                o[0] = ss;                                                  \
                _Pragma("unroll")                                           \
                for (int j = 1; j < 8; ++j) {                               \
                    int k = j + 8; float add_ = (VAL);                      \
                    k = j - 1;     float sub_ = (VAL);                      \
                    ss += add_ - sub_;                                      \
                    o[j] = ss;                                              \
                }                                                           \
                h8 v;                                                       \
                v.a = __floats2half2_rn(o[0], o[1]);                        \
                v.b = __floats2half2_rn(o[2], o[3]);                        \
                v.c = __floats2half2_rn(o[4], o[5]);                        \
                v.d = __floats2half2_rn(o[6], o[7]);                        \
                *(h8*)(wrow + CH * (SR * DIM)) = v;                         \
            }
            PROC(0, a[k])
            PROC(1, b[k])
            PROC(2, a[k] * a[k])
            PROC(3, b[k] * b[k])
            PROC(4, a[k] * b[k])
#undef PROC
        }
    }
    __syncthreads();

    // ---- H-stage: thread = (row r8 = tid/40, w 4q..4q+3), fp8 uint store ----
    {
        const int q = tid % 40, r8 = tid / 40;   // r8 in 0..7
        const int wp0 = 2 * q;                   // half2 index
        const size_t ob = (size_t)batch * 5 * VOL + (size_t)d * HW +
                          (size_t)(h0 + r8) * DIM + 4 * q;   // byte units
#pragma unroll
        for (int ch = 0; ch < 5; ++ch) {
            const __half2* col = (const __half2*)&wsl[ch][r8][0] + wp0;
            h4 v = *(const h4*)col;
            __half2 sa = v.a, sb = v.b;
#pragma unroll
            for (int k = 1; k < 9; ++k) {
                h4 u = *(const h4*)(col + k * (DIM / 2));
                sa = __hadd2(sa, u.a);
                sb = __hadd2(sb, u.b);
            }
            float2 f0 = __half22float2(sa);
            float2 f1 = __half22float2(sb);
            *(unsigned int*)(A8 + ob + (size_t)ch * VOL) =
                enc8(f0.x, f0.y, f1.x, f1.y);
        }
    }
}

__device__ inline void cc_accum(float s0, float s1, float s2, float s3,
                                float s4, float& acc) {
    const float inv_wsz = 1.0f / 729.0f;
    float cross = s4 - s0 * s1 * inv_wsz;
    float Ivar  = s2 - s0 * s0 * inv_wsz;
    float Jvar  = s3 - s1 * s1 * inv_wsz;
    float cc = cross * cross * __builtin_amdgcn_rcpf(Ivar * Jvar + 1e-5f);
    acc += fminf(fmaxf(cc, 0.0f), 1.0f);
}

__global__ __launch_bounds__(256) void k2_dsum_final(const unsigned char* __restrict__ A8,
                                                     float* __restrict__ partial) {
    const int batch = blockIdx.y;
    const unsigned int* B = (const unsigned int*)(A8 + (size_t)batch * 5 * VOL);
    const int PLW = VOL / 4;                 // uint plane stride
    const int HWW = HW / 4;                  // uint slice stride
    int t = blockIdx.x * 256 + threadIdx.x;  // < 40*160*16 = 102400
    int wq = t % 40;
    int rest = t / 40;
    int h = rest % DIM;
    int seg = rest / DIM;                    // 0..15
    int d0 = seg * SEG;
    const int base = h * 40 + wq;

    float4 s0 = {0,0,0,0}, s1 = {0,0,0,0}, s2 = {0,0,0,0},
           s3 = {0,0,0,0}, s4 = {0,0,0,0};
#define ACC4(sv, ch, idx, sgn)                                              \
    {                                                                       \
        float4 v_ = dec8(B[(ch) * PLW + (idx)]);                            \
        sv.x sgn v_.x; sv.y sgn v_.y; sv.z sgn v_.z; sv.w sgn v_.w;         \
    }
#pragma unroll
    for (int k = -4; k <= 4; ++k) {
        int dd = d0 + k;
        if (dd >= 0) {
            int idx = base + dd * HWW;
            ACC4(s0, 0, idx, +=) ACC4(s1, 1, idx, +=) ACC4(s2, 2, idx, +=)
            ACC4(s3, 3, idx, +=) ACC4(s4, 4, idx, +=)
        }
    }

    float acc = 0.f;
    for (int d = d0; d < d0 + SEG; ++d) {
        cc_accum(s0.x, s1.x, s2.x, s3.x, s4.x, acc);
        cc_accum(s0.y, s1.y, s2.y, s3.y, s4.y, acc);
        cc_accum(s0.z, s1.z, s2.z, s3.z, s4.z, acc);
        cc_accum(s0.w, s1.w, s2.w, s3.w, s4.w, acc);
        int lead = d + 5, trail = d - 4;
        if (lead < DIM) {
            int li = base + lead * HWW;
            ACC4(s0, 0, li, +=) ACC4(s1, 1, li, +=) ACC4(s2, 2, li, +=)
            ACC4(s3, 3, li, +=) ACC4(s4, 4, li, +=)
        }
        if (trail >= 0) {
            int ti = base + trail * HWW;
            ACC4(s0, 0, ti, -=) ACC4(s1, 1, ti, -=) ACC4(s2, 2, ti, -=)
            ACC4(s3, 3, ti, -=) ACC4(s4, 4, ti, -=)
        }
    }
#undef ACC4

#pragma unroll
    for (int off = 32; off > 0; off >>= 1) acc += __shfl_down(acc, off);
    __shared__ float ws4[4];
    if ((threadIdx.x & 63) == 0) ws4[threadIdx.x >> 6] = acc;
    __syncthreads();
    if (threadIdx.x == 0)
        partial[batch * 400 + blockIdx.x] = ws4[0] + ws4[1] + ws4[2] + ws4[3];
}

__global__ __launch_bounds__(256) void final_reduce(const float* __restrict__ partial,
                                                    int n, float* __restrict__ out) {
    float a = 0.f;
    for (int i = threadIdx.x; i < n; i += 256) a += partial[i];
#pragma unroll
    for (int off = 32; off > 0; off >>= 1) a += __shfl_down(a, off);
    __shared__ float ws4[4];
    if ((threadIdx.x & 63) == 0) ws4[threadIdx.x >> 6] = a;
    __syncthreads();
    if (threadIdx.x == 0)
        out[0] = 1.0f - (ws4[0] + ws4[1] + ws4[2] + ws4[3]) *
                            (1.0f / (float)(NBATCH * VOL));
}

extern "C" void kernel_launch(void* const* d_in, const int* in_sizes, int n_in,
                              void* d_out, int out_size, void* d_ws, size_t ws_size,
                              hipStream_t stream) {
    const float* I = (const float*)d_in[0];
    const float* J = (const float*)d_in[1];
    float* out = (float*)d_out;

    unsigned char* A8 = (unsigned char*)d_ws;                  // [2][5][VOL] fp8
    float* partial = (float*)(A8 + (size_t)NBATCH * 5 * VOL);  // [800]

    k1_boxsum2d<<<20 * DIM * NBATCH, THB, 0, stream>>>(I, J, A8);
    dim3 g2(400, NBATCH);                  // 800 blocks
    k2_dsum_final<<<g2, 256, 0, stream>>>(A8, partial);
    final_reduce<<<1, 256, 0, stream>>>(partial, NK2BLK, out);
}